// Round 1
// baseline (583.756 us; speedup 1.0000x reference)
//
#include <hip/hip_runtime.h>

// out[n, i] = b[n, i] * sum_j a[n, j]
// B = L = 8192, fp32. Memory-bound: 768 MiB compulsory traffic.
//
// Two-kernel split: the fused version stalled every block on
// vmcnt(0) + shuffle-chain + barrier between the a-read phase and the
// b-read/out-write phase, starving the memory system (~4.2 TB/s effective
// vs 6.3 TB/s copy ceiling). Splitting gives two pure streams:
//   1) rowsum: read a (256 MiB), write 8192 row sums (32 KB) to d_ws.
//   2) scale : read b + sums, write out -- copy-shaped, no barriers.

constexpr int L = 8192;
constexpr int BLOCK = 256;
constexpr int VEC = L / 4 / BLOCK;  // 8 float4 per thread per row
constexpr int ROWS_PER_BLOCK = 4;   // scale kernel: 4 rows per block

// --- Kernel 1: sums[row] = sum_j a[row, j] ---
__global__ __launch_bounds__(BLOCK) void rowsum_kernel(
    const float* __restrict__ a, float* __restrict__ sums) {
    const size_t row = blockIdx.x;
    const float4* __restrict__ arow =
        reinterpret_cast<const float4*>(a + row * (size_t)L);
    const int tid = threadIdx.x;

    float4 va[VEC];
#pragma unroll
    for (int k = 0; k < VEC; ++k) {
        va[k] = arow[tid + k * BLOCK];  // coalesced, 8 loads in flight
    }
    float s = 0.0f;
#pragma unroll
    for (int k = 0; k < VEC; ++k) {
        s += (va[k].x + va[k].y) + (va[k].z + va[k].w);
    }

    // wave-64 shuffle reduction
#pragma unroll
    for (int off = 32; off > 0; off >>= 1) {
        s += __shfl_down(s, off, 64);
    }

    __shared__ float wave_sums[BLOCK / 64];  // 4 waves
    const int lane = tid & 63;
    const int wave = tid >> 6;
    if (lane == 0) wave_sums[wave] = s;
    __syncthreads();

    if (tid == 0) {
        sums[row] = (wave_sums[0] + wave_sums[1]) + (wave_sums[2] + wave_sums[3]);
    }
}

// --- Kernel 2: out[row, :] = b[row, :] * sums[row] ---
// Pure stream: hoist the 4 row-sums, then an uninterrupted
// load->scale->store pipeline. No LDS, no barriers, VGPR <= ~40.
__global__ __launch_bounds__(BLOCK) void scale_kernel(
    const float* __restrict__ b, const float* __restrict__ sums,
    float* __restrict__ out) {
    const size_t row0 = (size_t)blockIdx.x * ROWS_PER_BLOCK;
    const int tid = threadIdx.x;

    float s[ROWS_PER_BLOCK];
#pragma unroll
    for (int r = 0; r < ROWS_PER_BLOCK; ++r) {
        s[r] = sums[row0 + r];  // block-uniform -> scalar-cached
    }

#pragma unroll
    for (int r = 0; r < ROWS_PER_BLOCK; ++r) {
        const size_t row = row0 + r;
        const float4* __restrict__ brow =
            reinterpret_cast<const float4*>(b + row * (size_t)L);
        float4* __restrict__ orow =
            reinterpret_cast<float4*>(out + row * (size_t)L);
        const float sr = s[r];
#pragma unroll
        for (int k = 0; k < VEC; ++k) {
            float4 v = brow[tid + k * BLOCK];
            v.x *= sr;
            v.y *= sr;
            v.z *= sr;
            v.w *= sr;
            orow[tid + k * BLOCK] = v;
        }
    }
}

// --- Fallback: original fused kernel (used only if workspace too small) ---
__global__ __launch_bounds__(BLOCK) void outer_row_scale_kernel(
    const float* __restrict__ a,
    const float* __restrict__ b,
    float* __restrict__ out) {
    const size_t row = blockIdx.x;
    const float4* __restrict__ arow = reinterpret_cast<const float4*>(a + row * (size_t)L);
    const float4* __restrict__ brow = reinterpret_cast<const float4*>(b + row * (size_t)L);
    float4* __restrict__ orow = reinterpret_cast<float4*>(out + row * (size_t)L);

    const int tid = threadIdx.x;

    float s = 0.0f;
    float4 va[VEC];
#pragma unroll
    for (int k = 0; k < VEC; ++k) {
        va[k] = arow[tid + k * BLOCK];
    }
#pragma unroll
    for (int k = 0; k < VEC; ++k) {
        s += (va[k].x + va[k].y) + (va[k].z + va[k].w);
    }
#pragma unroll
    for (int off = 32; off > 0; off >>= 1) {
        s += __shfl_down(s, off, 64);
    }
    __shared__ float wave_sums[BLOCK / 64];
    const int lane = tid & 63;
    const int wave = tid >> 6;
    if (lane == 0) wave_sums[wave] = s;
    __syncthreads();

    const float total = (wave_sums[0] + wave_sums[1]) + (wave_sums[2] + wave_sums[3]);

#pragma unroll
    for (int k = 0; k < VEC; ++k) {
        float4 vb = brow[tid + k * BLOCK];
        float4 vo;
        vo.x = vb.x * total;
        vo.y = vb.y * total;
        vo.z = vb.z * total;
        vo.w = vb.w * total;
        orow[tid + k * BLOCK] = vo;
    }
}

extern "C" void kernel_launch(void* const* d_in, const int* in_sizes, int n_in,
                              void* d_out, int out_size, void* d_ws, size_t ws_size,
                              hipStream_t stream) {
    const float* a = (const float*)d_in[0];
    const float* b = (const float*)d_in[1];
    float* out = (float*)d_out;
    const int B = in_sizes[0] / L;  // 8192

    if (ws_size >= (size_t)B * sizeof(float)) {
        float* sums = (float*)d_ws;
        rowsum_kernel<<<B, BLOCK, 0, stream>>>(a, sums);
        scale_kernel<<<B / ROWS_PER_BLOCK, BLOCK, 0, stream>>>(b, sums, out);
    } else {
        // Workspace too small for row sums -- fall back to fused kernel.
        outer_row_scale_kernel<<<B, BLOCK, 0, stream>>>(a, b, out);
    }
}

// Round 3
// 578.305 us; speedup vs baseline: 1.0094x; 1.0094x over previous
//
#include <hip/hip_runtime.h>

// out[n, i] = b[n, i] * sum_j a[n, j]
// B = L = 8192, fp32. Memory-bound: 768 MiB compulsory traffic.
//
// Round-1 lesson: two-kernel split was NEUTRAL (sum == fused 193 us), so the
// limiter was never the inter-phase barrier. Both variants used short-lived
// burst-then-die blocks (8192 blocks x one 8-load burst). The rocclr fill in
// the same profile hits 6.5 TB/s at 10% occupancy with long-lived grid-stride
// threads. This version: ~2048 persistent blocks, dense uninterrupted VMEM
// streams, reductions only at end-of-wave-life, nontemporal stores for the
// never-re-read output.
//
// Round-2 fix: __builtin_nontemporal_store requires a native clang vector
// type, not HIP_vector_type<float,4> -- use ext_vector_type(4) for the store.

constexpr int L = 8192;
constexpr int BLOCK = 256;
constexpr int L4 = L / 4;             // 2048 float4 per row
constexpr int WAVES = BLOCK / 64;     // 4 waves per block
constexpr int F4_PER_LANE = L4 / 64;  // 32 float4 per lane (wave-per-row)
constexpr int VEC = L4 / BLOCK;       // 8 float4 per thread (block-per-row)

typedef float fx4 __attribute__((ext_vector_type(4)));

// --- Kernel 1: sums[row] = sum_j a[row, j] ---
// One WAVE per row: 2048 blocks x 4 waves = 8192 rows. No LDS, no barriers.
// Each wave streams 32 float4/lane with 4 independent accumulators; the only
// cross-lane work (6 shuffles) happens once, at end of wave life.
__global__ __launch_bounds__(BLOCK) void rowsum_kernel(
    const float* __restrict__ a, float* __restrict__ sums) {
    const int wave = threadIdx.x >> 6;
    const int lane = threadIdx.x & 63;
    const size_t row = (size_t)blockIdx.x * WAVES + wave;
    const fx4* __restrict__ arow =
        reinterpret_cast<const fx4*>(a + row * (size_t)L);

    float p0 = 0.0f, p1 = 0.0f, p2 = 0.0f, p3 = 0.0f;
#pragma unroll
    for (int k = 0; k < F4_PER_LANE; k += 4) {
        fx4 v0 = arow[lane + (k + 0) * 64];
        fx4 v1 = arow[lane + (k + 1) * 64];
        fx4 v2 = arow[lane + (k + 2) * 64];
        fx4 v3 = arow[lane + (k + 3) * 64];
        p0 += (v0.x + v0.y) + (v0.z + v0.w);
        p1 += (v1.x + v1.y) + (v1.z + v1.w);
        p2 += (v2.x + v2.y) + (v2.z + v2.w);
        p3 += (v3.x + v3.y) + (v3.z + v3.w);
    }
    float s = (p0 + p1) + (p2 + p3);

#pragma unroll
    for (int off = 32; off > 0; off >>= 1) {
        s += __shfl_down(s, off, 64);
    }
    if (lane == 0) sums[row] = s;
}

// --- Kernel 2: out[row, :] = b[row, :] * sums[row] ---
// 2048 persistent blocks, grid-stride over rows (4 iterations). One block
// covers exactly one row per iteration (256 threads x 8 float4 = 2048 float4).
// Row sum is prefetched one iteration ahead; out uses nontemporal stores
// (never re-read -> don't let it evict a/b from L3).
__global__ __launch_bounds__(BLOCK) void scale_kernel(
    const float* __restrict__ b, const float* __restrict__ sums,
    float* __restrict__ out, int nrows) {
    const int tid = threadIdx.x;
    int row = blockIdx.x;
    float sr = sums[row];
    for (; row < nrows; row += gridDim.x) {
        const int next = row + gridDim.x;
        const float sn = (next < nrows) ? sums[next] : 0.0f;

        const fx4* __restrict__ brow =
            reinterpret_cast<const fx4*>(b + (size_t)row * (size_t)L);
        fx4* __restrict__ orow =
            reinterpret_cast<fx4*>(out + (size_t)row * (size_t)L);
#pragma unroll
        for (int k = 0; k < VEC; ++k) {
            fx4 v = brow[tid + k * BLOCK];
            v *= sr;
            __builtin_nontemporal_store(v, &orow[tid + k * BLOCK]);
        }
        sr = sn;
    }
}

// --- Fallback: fused kernel (used only if workspace too small) ---
__global__ __launch_bounds__(BLOCK) void outer_row_scale_kernel(
    const float* __restrict__ a,
    const float* __restrict__ b,
    float* __restrict__ out) {
    const size_t row = blockIdx.x;
    const float4* __restrict__ arow = reinterpret_cast<const float4*>(a + row * (size_t)L);
    const float4* __restrict__ brow = reinterpret_cast<const float4*>(b + row * (size_t)L);
    float4* __restrict__ orow = reinterpret_cast<float4*>(out + row * (size_t)L);

    const int tid = threadIdx.x;

    float s = 0.0f;
    float4 va[VEC];
#pragma unroll
    for (int k = 0; k < VEC; ++k) {
        va[k] = arow[tid + k * BLOCK];
    }
#pragma unroll
    for (int k = 0; k < VEC; ++k) {
        s += (va[k].x + va[k].y) + (va[k].z + va[k].w);
    }
#pragma unroll
    for (int off = 32; off > 0; off >>= 1) {
        s += __shfl_down(s, off, 64);
    }
    __shared__ float wave_sums[BLOCK / 64];
    const int lane = tid & 63;
    const int wave = tid >> 6;
    if (lane == 0) wave_sums[wave] = s;
    __syncthreads();

    const float total = (wave_sums[0] + wave_sums[1]) + (wave_sums[2] + wave_sums[3]);

#pragma unroll
    for (int k = 0; k < VEC; ++k) {
        float4 vb = brow[tid + k * BLOCK];
        float4 vo;
        vo.x = vb.x * total;
        vo.y = vb.y * total;
        vo.z = vb.z * total;
        vo.w = vb.w * total;
        orow[tid + k * BLOCK] = vo;
    }
}

extern "C" void kernel_launch(void* const* d_in, const int* in_sizes, int n_in,
                              void* d_out, int out_size, void* d_ws, size_t ws_size,
                              hipStream_t stream) {
    const float* a = (const float*)d_in[0];
    const float* b = (const float*)d_in[1];
    float* out = (float*)d_out;
    const int B = in_sizes[0] / L;  // 8192

    if (ws_size >= (size_t)B * sizeof(float)) {
        float* sums = (float*)d_ws;
        rowsum_kernel<<<B / WAVES, BLOCK, 0, stream>>>(a, sums);
        const int grid2 = 2048;
        scale_kernel<<<grid2, BLOCK, 0, stream>>>(b, sums, out, B);
    } else {
        outer_row_scale_kernel<<<B, BLOCK, 0, stream>>>(a, b, out);
    }
}